// Round 5
// baseline (120.307 us; speedup 1.0000x reference)
//
#include <hip/hip_runtime.h>
#include <hip/hip_bf16.h>
#include <stdint.h>

#define BATCH 16384
#define MAXA 32
#define FEAT 768
#define HIDDEN 1024

// ---------------------------------------------------------------------------
// Prep 1: per-hidden-column max -> scale/invscale; block 1024 inits the dummy
// zero column wQ[768][*] = 128 (q=0 biased).
// ---------------------------------------------------------------------------
__global__ __launch_bounds__(256) void scale_k(const float* __restrict__ ftw,
                                               float* __restrict__ scale,
                                               float* __restrict__ invsc,
                                               uint8_t* __restrict__ wQ) {
  if (blockIdx.x == HIDDEN) {
    if (threadIdx.x < 64) {
      uint4 v; v.x = v.y = v.z = v.w = 0x80808080u;
      ((uint4*)(wQ + (size_t)FEAT * HIDDEN))[threadIdx.x] = v;
    }
    return;
  }
  const int h = blockIdx.x;
  float a = 0.f;
#pragma unroll
  for (int p = 0; p < 3; ++p)
    a = fmaxf(a, fabsf(ftw[h * FEAT + p * 256 + threadIdx.x]));
#pragma unroll
  for (int off = 32; off > 0; off >>= 1)
    a = fmaxf(a, __shfl_xor(a, off, 64));
  __shared__ float red[4];
  if ((threadIdx.x & 63) == 0) red[threadIdx.x >> 6] = a;
  __syncthreads();
  if (threadIdx.x == 0) {
    float m = fmaxf(fmaxf(red[0], red[1]), fmaxf(red[2], red[3]));
    m = fmaxf(m, 1e-20f);
    scale[h] = m / 127.f;
    invsc[h] = 127.f / m;
  }
}

// ---------------------------------------------------------------------------
// Prep 2: quantize + transpose, LDS-tiled, coalesced reads + 16 B stores.
// ---------------------------------------------------------------------------
__global__ __launch_bounds__(256) void tilequant(const float* __restrict__ ftw,
                                                 const float* __restrict__ invsc,
                                                 uint8_t* __restrict__ wQ) {
  const int f0 = (blockIdx.x % (FEAT / 64)) * 64;
  const int h0 = (blockIdx.x / (FEAT / 64)) * 64;
  __shared__ uint8_t tile[64][80];
  __shared__ float inv[64];
  if (threadIdx.x < 64) inv[threadIdx.x] = invsc[h0 + threadIdx.x];
  __syncthreads();
  const int ff = threadIdx.x & 63;
  const int hb = threadIdx.x >> 6;
#pragma unroll
  for (int p = 0; p < 16; ++p) {
    int hh = p * 4 + hb;
    float w = ftw[(size_t)(h0 + hh) * FEAT + f0 + ff];
    int q = __float2int_rn(w * inv[hh]);
    tile[ff][hh] = (uint8_t)(q + 128);
  }
  __syncthreads();
  const int fs = threadIdx.x >> 2, part = threadIdx.x & 3;
  uint4 v = *(const uint4*)&tile[fs][part * 16];
  *(uint4*)(wQ + (size_t)(f0 + fs) * HIDDEN + h0 + part * 16) = v;
}

// packed u16 accumulate: plain u32 add == 2xu16 add (field max 32*255 = 8160).
__device__ __forceinline__ void acc16(uint32_t* acc, uint4 w) {
  acc[0] += __builtin_amdgcn_perm(0u, w.x, 0x0c010c00u);
  acc[1] += __builtin_amdgcn_perm(0u, w.x, 0x0c030c02u);
  acc[2] += __builtin_amdgcn_perm(0u, w.y, 0x0c010c00u);
  acc[3] += __builtin_amdgcn_perm(0u, w.y, 0x0c030c02u);
  acc[4] += __builtin_amdgcn_perm(0u, w.z, 0x0c010c00u);
  acc[5] += __builtin_amdgcn_perm(0u, w.z, 0x0c030c02u);
  acc[6] += __builtin_amdgcn_perm(0u, w.w, 0x0c010c00u);
  acc[7] += __builtin_amdgcn_perm(0u, w.w, 0x0c030c02u);
}

// One wave per batch row. Lane L owns h = L*16 .. +15 for BOTH sides.
// Features iterated in ASCENDING order (per-half bitonic sort) so co-resident
// waves sweep the 769 KB table in phase -> L1 temporal locality.
__global__ __launch_bounds__(256, 6) void nn_fwd(
    const int* __restrict__ stm, const int* __restrict__ nstm,
    const uint8_t* __restrict__ wQ, const float* __restrict__ scale,
    const float* __restrict__ bias, const float* __restrict__ outw,
    const float* __restrict__ outb, float* __restrict__ out)
{
  const int lane = threadIdx.x & 63;
  const int row  = blockIdx.x * 4 + (threadIdx.x >> 6);
  const int half = lane >> 5;       // 0 = stm, 1 = nstm
  const int pos  = lane & 31;

  const int* __restrict__ src = half ? nstm : stm;
  int idx = src[row * MAXA + pos];
  bool valid = idx >= 0;            // -1 padding -> no contribution
  // dedupe within each half: reference .at[].max() counts duplicates once
#pragma unroll
  for (int j = 0; j < 31; ++j) {
    int other = __shfl(idx, (half << 5) | j, 64);
    if (j < pos && other == idx) valid = false;
  }
  int fmap = valid ? idx : FEAT;    // dummy zero column (sorts to the end)

  // per-half 32-lane bitonic ascending sort (xor masks < 32 stay in-half)
#pragma unroll
  for (int k = 2; k <= 32; k <<= 1) {
#pragma unroll
    for (int j = k >> 1; j > 0; j >>= 1) {
      int other = __shfl_xor(fmap, j, 64);
      bool lower = (pos & j) == 0;
      bool desc  = (pos & k) != 0;
      int mn = min(fmap, other), mx = max(fmap, other);
      fmap = (lower != desc) ? mn : mx;
    }
  }

  uint32_t accs[8], accn[8];
#pragma unroll
  for (int k = 0; k < 8; ++k) { accs[k] = 0u; accn[k] = 0u; }

  // 8 groups x (8 loads then 8 accs): ~8 KB in flight per wave, scalar bases.
#pragma unroll
  for (int jb = 0; jb < 32; jb += 4) {
    uint4 ws[4], wn[4];
#pragma unroll
    for (int u = 0; u < 4; ++u) {
      int fs_ = __builtin_amdgcn_readlane(fmap, jb + u);
      int fn_ = __builtin_amdgcn_readlane(fmap, 32 + jb + u);
      ws[u] = ((const uint4*)(wQ + (size_t)fs_ * HIDDEN))[lane];
      wn[u] = ((const uint4*)(wQ + (size_t)fn_ * HIDDEN))[lane];
    }
#pragma unroll
    for (int u = 0; u < 4; ++u) { acc16(accs, ws[u]); acc16(accn, wn[u]); }
  }

  const int DB = 32 * 128;   // constant de-bias (every slot contributes +128)

  // Epilogue, per-float4 to keep VGPR pressure low.
  const int hbase = lane * 16;
  const float4* s4 = (const float4*)(scale + hbase);
  const float4* b4 = (const float4*)(bias + hbase);
  const float4* oS = (const float4*)(outw + hbase);
  const float4* oN = (const float4*)(outw + HIDDEN + hbase);
  float partial = 0.f;
#pragma unroll
  for (int q = 0; q < 4; ++q) {
    float4 sv = s4[q], bv = b4[q], ov = oS[q], nv = oN[q];
    const float* sp = &sv.x; const float* bp = &bv.x;
    const float* op = &ov.x; const float* np = &nv.x;
#pragma unroll
    for (int e = 0; e < 4; ++e) {
      int k = q * 4 + e;
      uint32_t as = accs[k >> 1], an = accn[k >> 1];
      int qs = (int)((k & 1) ? (as >> 16) : (as & 0xffffu)) - DB;
      int qn = (int)((k & 1) ? (an >> 16) : (an & 0xffffu)) - DB;
      float hs = fminf(fmaxf(fmaf((float)qs, sp[e], bp[e]), 0.f), 1.f);
      float hn = fminf(fmaxf(fmaf((float)qn, sp[e], bp[e]), 0.f), 1.f);
      partial += hs * op[e] + hn * np[e];
    }
  }
#pragma unroll
  for (int off = 32; off > 0; off >>= 1)
    partial += __shfl_down(partial, off, 64);
  if (lane == 0) {
    float y = partial + outb[0];
    out[row] = 1.f / (1.f + __expf(-y));
  }
}

extern "C" void kernel_launch(void* const* d_in, const int* in_sizes, int n_in,
                              void* d_out, int out_size, void* d_ws, size_t ws_size,
                              hipStream_t stream) {
  const int*   stm  = (const int*)d_in[0];
  const int*   nstm = (const int*)d_in[1];
  const float* ftw  = (const float*)d_in[2];   // (1024, 768) fp32
  const float* ftb  = (const float*)d_in[3];   // (1024,) fp32
  const float* outw = (const float*)d_in[4];   // (2048,) fp32
  const float* outb = (const float*)d_in[5];   // (1,) fp32

  uint8_t* wQ    = (uint8_t*)d_ws;                               // 769 KB
  float*   scale = (float*)(wQ + (size_t)(FEAT + 1) * HIDDEN);   // 4 KB
  float*   invsc = scale + HIDDEN;                               // 4 KB

  scale_k<<<HIDDEN + 1, 256, 0, stream>>>(ftw, scale, invsc, wQ);
  tilequant<<<(FEAT / 64) * (HIDDEN / 64), 256, 0, stream>>>(ftw, invsc, wQ);
  nn_fwd<<<BATCH / 4, 256, 0, stream>>>(stm, nstm, wQ, scale, ftb, outw, outb,
                                        (float*)d_out);
}